// Round 5
// baseline (53.685 us; speedup 1.0000x reference)
//
#include <hip/hip_runtime.h>

// Problem constants (match reference setup_inputs).
constexpr int B       = 4096;
constexpr int W_ENC   = 8192;
constexpr int MAX_LEN = 4096;
constexpr int VPR     = W_ENC / 4;   // float4 vectors per output row = 2048
constexpr int BLOCK   = 256;
constexpr int VPT     = VPR / BLOCK; // vectors per thread = 8

// Native clang vector type (16B, dword-aligned ops).
typedef float fx4 __attribute__((ext_vector_type(4)));

// Aligned fx4 from the virtual concat row [prev(2048 vecs) | ragged(1024 vecs)].
// Concat boundary is vector-aligned -> each aligned vector lives entirely in one
// array; pointer-select is a cndmask on the address, no divergence cost.
__device__ __forceinline__ fx4 cvec(const fx4* __restrict__ pv,
                                    const fx4* __restrict__ rv, int v) {
    const fx4* p = (v < VPR) ? (pv + v) : (rv + (v - VPR));
    return *p;
}

// One row, remainder R = L&3 known at compile time (switched once per block).
// Issue all loads first (MLP), then rotate+store. All indices compile-time ->
// everything stays in registers (no scratch).
template <int R>
__device__ __forceinline__ void do_row(const fx4* __restrict__ pv,
                                       const fx4* __restrict__ rv,
                                       fx4* __restrict__ ov,
                                       int q, int tid) {
    fx4 A[VPT];
    fx4 Bv[VPT];
    #pragma unroll
    for (int m = 0; m < VPT; ++m) {
        const int vA = q + tid + m * BLOCK;   // <= 1023+255+1792 = 3070
        A[m] = cvec(pv, rv, vA);
        if (R != 0) Bv[m] = cvec(pv, rv, vA + 1);   // <= 3071 < 3072, never OOB
    }
    #pragma unroll
    for (int m = 0; m < VPT; ++m) {
        fx4 o;
        if      (R == 0) o = A[m];
        else if (R == 1) o = fx4{A[m].y, A[m].z, A[m].w, Bv[m].x};
        else if (R == 2) o = fx4{A[m].z, A[m].w, Bv[m].x, Bv[m].y};
        else             o = fx4{A[m].w, Bv[m].x, Bv[m].y, Bv[m].z};
        // Plain store (R5 A/B vs R4's nontemporal: fill kernel shows plain
        // stores sustain 6.8 TB/s; testing whether the nt path throttled drain).
        ov[tid + m * BLOCK] = o;
    }
}

// y[i][j] = concat(prev[i], ragged[i])[j + L_i], j in [0, W_ENC)
// lens_out[i] = (float)L_i
__global__ __launch_bounds__(BLOCK) void frames_gather_kernel(
        const float* __restrict__ prev,
        const float* __restrict__ ragged,
        const int*   __restrict__ row_lengths,
        float*       __restrict__ out) {
    const int i = blockIdx.x;            // one block per row
    const int L = row_lengths[i];        // block-uniform -> scalar s_load

    if (threadIdx.x == 0) {
        out[(size_t)B * W_ENC + i] = (float)L;   // lens output
    }

    const fx4* __restrict__ pv = (const fx4*)(prev   + (size_t)i * W_ENC);
    const fx4* __restrict__ rv = (const fx4*)(ragged + (size_t)i * MAX_LEN);
    fx4* __restrict__ ov       = (fx4*)(out + (size_t)i * W_ENC);

    const int q   = L >> 2;   // vector shift
    const int tid = threadIdx.x;

    switch (L & 3) {          // wave-uniform, branched exactly once
    case 0:  do_row<0>(pv, rv, ov, q, tid); break;
    case 1:  do_row<1>(pv, rv, ov, q, tid); break;
    case 2:  do_row<2>(pv, rv, ov, q, tid); break;
    default: do_row<3>(pv, rv, ov, q, tid); break;
    }
}

extern "C" void kernel_launch(void* const* d_in, const int* in_sizes, int n_in,
                              void* d_out, int out_size, void* d_ws, size_t ws_size,
                              hipStream_t stream) {
    const float* prev        = (const float*)d_in[0];
    const float* ragged_vals = (const float*)d_in[1];
    const int*   row_lengths = (const int*)d_in[2];
    float*       out         = (float*)d_out;

    frames_gather_kernel<<<B, BLOCK, 0, stream>>>(prev, ragged_vals, row_lengths, out);
}

// Round 6
// 46.101 us; speedup vs baseline: 1.1645x; 1.1645x over previous
//
#include <hip/hip_runtime.h>

// Problem constants (match reference setup_inputs).
constexpr int B       = 4096;
constexpr int W_ENC   = 8192;
constexpr int MAX_LEN = 4096;
constexpr int VPR     = W_ENC / 4;   // float4 vectors per output row = 2048
constexpr int BLOCK   = 256;
constexpr int VPT     = VPR / BLOCK; // vectors per thread per row = 8
constexpr int RPB     = 2;           // rows per block

// Native clang vector type: required by __builtin_nontemporal_store.
typedef float fx4 __attribute__((ext_vector_type(4)));

// Aligned fx4 from the virtual concat row [prev(2048 vecs) | ragged(1024 vecs)].
// Concat boundary is vector-aligned -> each aligned vector lives entirely in one
// array; pointer-select is a cndmask on the address, no divergence cost.
__device__ __forceinline__ fx4 cvec(const fx4* __restrict__ pv,
                                    const fx4* __restrict__ rv, int v) {
    const fx4* p = (v < VPR) ? (pv + v) : (rv + (v - VPR));
    return *p;
}

// One row, remainder R = L&3 known at compile time (switched once per block).
// Loads batched before rotates/stores; NT stores are fire-and-forget (single
// vmcnt drain at endpgm), so the next row's loads overlap this row's drain.
template <int R>
__device__ __forceinline__ void do_row(const fx4* __restrict__ pv,
                                       const fx4* __restrict__ rv,
                                       fx4* __restrict__ ov,
                                       int q, int tid) {
    fx4 A[VPT];
    fx4 Bv[VPT];
    #pragma unroll
    for (int m = 0; m < VPT; ++m) {
        const int vA = q + tid + m * BLOCK;   // <= 1023+255+1792 = 3070
        A[m] = cvec(pv, rv, vA);
        if (R != 0) Bv[m] = cvec(pv, rv, vA + 1);   // <= 3071 < 3072, never OOB
    }
    #pragma unroll
    for (int m = 0; m < VPT; ++m) {
        fx4 o;
        if      (R == 0) o = A[m];
        else if (R == 1) o = fx4{A[m].y, A[m].z, A[m].w, Bv[m].x};
        else if (R == 2) o = fx4{A[m].z, A[m].w, Bv[m].x, Bv[m].y};
        else             o = fx4{A[m].w, Bv[m].x, Bv[m].y, Bv[m].z};
        // Non-temporal: output is write-once; keeps the 128MB touched input
        // set L3-resident across replays (R5 A/B: plain stores cost +9us).
        __builtin_nontemporal_store(o, ov + tid + m * BLOCK);
    }
}

__device__ __forceinline__ void one_row(const float* __restrict__ prev,
                                        const float* __restrict__ ragged,
                                        const int*   __restrict__ row_lengths,
                                        float*       __restrict__ out,
                                        int i, int tid) {
    const int L = row_lengths[i];        // block-uniform -> scalar s_load

    if (tid == 0) out[(size_t)B * W_ENC + i] = (float)L;   // lens output

    const fx4* __restrict__ pv = (const fx4*)(prev   + (size_t)i * W_ENC);
    const fx4* __restrict__ rv = (const fx4*)(ragged + (size_t)i * MAX_LEN);
    fx4* __restrict__ ov       = (fx4*)(out + (size_t)i * W_ENC);

    const int q = L >> 2;

    switch (L & 3) {          // wave-uniform, branched once per row
    case 0:  do_row<0>(pv, rv, ov, q, tid); break;
    case 1:  do_row<1>(pv, rv, ov, q, tid); break;
    case 2:  do_row<2>(pv, rv, ov, q, tid); break;
    default: do_row<3>(pv, rv, ov, q, tid); break;
    }
}

// y[i][j] = concat(prev[i], ragged[i])[j + L_i], j in [0, W_ENC)
// lens_out[i] = (float)L_i
__global__ __launch_bounds__(BLOCK) void frames_gather_kernel(
        const float* __restrict__ prev,
        const float* __restrict__ ragged,
        const int*   __restrict__ row_lengths,
        float*       __restrict__ out) {
    const int i0  = blockIdx.x * RPB;    // two rows per block
    const int tid = threadIdx.x;
    one_row(prev, ragged, row_lengths, out, i0 + 0, tid);
    one_row(prev, ragged, row_lengths, out, i0 + 1, tid);
}

extern "C" void kernel_launch(void* const* d_in, const int* in_sizes, int n_in,
                              void* d_out, int out_size, void* d_ws, size_t ws_size,
                              hipStream_t stream) {
    const float* prev        = (const float*)d_in[0];
    const float* ragged_vals = (const float*)d_in[1];
    const int*   row_lengths = (const int*)d_in[2];
    float*       out         = (float*)d_out;

    frames_gather_kernel<<<B / RPB, BLOCK, 0, stream>>>(prev, ragged_vals, row_lengths, out);
}

// Round 8
// 45.058 us; speedup vs baseline: 1.1915x; 1.0231x over previous
//
#include <hip/hip_runtime.h>

// Problem constants (match reference setup_inputs).
constexpr int B       = 4096;
constexpr int W_ENC   = 8192;
constexpr int MAX_LEN = 4096;
constexpr int VPR     = W_ENC / 4;   // float4 vectors per output row = 2048
constexpr int BLOCK   = 256;
constexpr int VPT     = VPR / BLOCK; // vectors per thread = 8

// Native clang vector type (16B).
typedef float fx4 __attribute__((ext_vector_type(4)));

// Aligned fx4 from the virtual concat row [prev(2048 vecs) | ragged(1024 vecs)].
// Concat boundary is vector-aligned -> each aligned vector lives entirely in one
// array; pointer-select is a cndmask on the address, no divergence cost.
__device__ __forceinline__ fx4 cvec(const fx4* __restrict__ pv,
                                    const fx4* __restrict__ rv, int v) {
    const fx4* p = (v < VPR) ? (pv + v) : (rv + (v - VPR));
    return *p;
}

// One row, remainder R = L&3 known at compile time (switched once per block).
// Loads batched (MLP), rotates computed, then ALL 8 streaming stores issued in
// ONE asm block ending in s_waitcnt vmcnt(0): every addr/data register is an
// asm operand alive for the whole block, so the compiler cannot recycle a
// store's data regs while the store is in flight (R7 bug: per-store asm let
// the register allocator clobber in-flight store data -> garbage output).
// sc0 sc1 nt = system-scope non-temporal: stream writes past L2/MALL so the
// 128MB read set stays cache-resident across replays.
template <int R>
__device__ __forceinline__ void do_row(const fx4* __restrict__ pv,
                                       const fx4* __restrict__ rv,
                                       fx4* __restrict__ ov,
                                       int q, int tid) {
    fx4 A[VPT];
    fx4 Bv[VPT];
    #pragma unroll
    for (int m = 0; m < VPT; ++m) {
        const int vA = q + tid + m * BLOCK;   // <= 1023+255+1792 = 3070
        A[m] = cvec(pv, rv, vA);
        if (R != 0) Bv[m] = cvec(pv, rv, vA + 1);   // <= 3071 < 3072, never OOB
    }
    fx4 o[VPT];
    #pragma unroll
    for (int m = 0; m < VPT; ++m) {
        if      (R == 0) o[m] = A[m];
        else if (R == 1) o[m] = fx4{A[m].y, A[m].z, A[m].w, Bv[m].x};
        else if (R == 2) o[m] = fx4{A[m].z, A[m].w, Bv[m].x, Bv[m].y};
        else             o[m] = fx4{A[m].w, Bv[m].x, Bv[m].y, Bv[m].z};
    }
    fx4* p = ov + tid;
    asm volatile(
        "global_store_dwordx4 %0, %8, off sc0 sc1 nt\n\t"
        "global_store_dwordx4 %1, %9, off sc0 sc1 nt\n\t"
        "global_store_dwordx4 %2, %10, off sc0 sc1 nt\n\t"
        "global_store_dwordx4 %3, %11, off sc0 sc1 nt\n\t"
        "global_store_dwordx4 %4, %12, off sc0 sc1 nt\n\t"
        "global_store_dwordx4 %5, %13, off sc0 sc1 nt\n\t"
        "global_store_dwordx4 %6, %14, off sc0 sc1 nt\n\t"
        "global_store_dwordx4 %7, %15, off sc0 sc1 nt\n\t"
        "s_waitcnt vmcnt(0)"
        :
        : "v"(p),             "v"(p + 1 * BLOCK), "v"(p + 2 * BLOCK), "v"(p + 3 * BLOCK),
          "v"(p + 4 * BLOCK), "v"(p + 5 * BLOCK), "v"(p + 6 * BLOCK), "v"(p + 7 * BLOCK),
          "v"(o[0]), "v"(o[1]), "v"(o[2]), "v"(o[3]),
          "v"(o[4]), "v"(o[5]), "v"(o[6]), "v"(o[7])
        : "memory");
}

// y[i][j] = concat(prev[i], ragged[i])[j + L_i], j in [0, W_ENC)
// lens_out[i] = (float)L_i
__global__ __launch_bounds__(BLOCK) void frames_gather_kernel(
        const float* __restrict__ prev,
        const float* __restrict__ ragged,
        const int*   __restrict__ row_lengths,
        float*       __restrict__ out) {
    const int i = blockIdx.x;            // one block per row (R4 config: best)
    const int L = row_lengths[i];        // block-uniform -> scalar s_load

    if (threadIdx.x == 0) {
        out[(size_t)B * W_ENC + i] = (float)L;   // lens output (tiny, plain store)
    }

    const fx4* __restrict__ pv = (const fx4*)(prev   + (size_t)i * W_ENC);
    const fx4* __restrict__ rv = (const fx4*)(ragged + (size_t)i * MAX_LEN);
    fx4* __restrict__ ov       = (fx4*)(out + (size_t)i * W_ENC);

    const int q   = L >> 2;   // vector shift
    const int tid = threadIdx.x;

    switch (L & 3) {          // wave-uniform, branched exactly once
    case 0:  do_row<0>(pv, rv, ov, q, tid); break;
    case 1:  do_row<1>(pv, rv, ov, q, tid); break;
    case 2:  do_row<2>(pv, rv, ov, q, tid); break;
    default: do_row<3>(pv, rv, ov, q, tid); break;
    }
}

extern "C" void kernel_launch(void* const* d_in, const int* in_sizes, int n_in,
                              void* d_out, int out_size, void* d_ws, size_t ws_size,
                              hipStream_t stream) {
    const float* prev        = (const float*)d_in[0];
    const float* ragged_vals = (const float*)d_in[1];
    const int*   row_lengths = (const int*)d_in[2];
    float*       out         = (float*)d_out;

    frames_gather_kernel<<<B, BLOCK, 0, stream>>>(prev, ragged_vals, row_lengths, out);
}